// Round 1
// baseline (229.284 us; speedup 1.0000x reference)
//
#include <hip/hip_runtime.h>
#include <math.h>

// Problem constants (from reference)
#define LSEQ   129      // PL + 1
#define PLEN   128
#define NHEAD  8
#define DHEAD  32
#define INNER  256      // NHEAD * V_DIM
#define HID    1024     // 4 * INNER

// -------------------------------------------------------------------------
// Kernel 1: QKV projection (rank-2) + RoPE + single-query (l=0) attention.
// One block per bn (B*PN = 1024), 256 threads = one channel c = h*32+d each.
// Online softmax; K/V recomputed on the fly (2 FMAs each). Writes last[bn,c].
// -------------------------------------------------------------------------
__global__ __launch_bounds__(256) void attn_kernel(
    const float* __restrict__ x,      // (BN, PL, 2)
    const float* __restrict__ t,      // (BN, L)
    const int*   __restrict__ mask,   // (BN, L)
    const float* __restrict__ emb,    // (2,)
    const float* __restrict__ Wq,     // (2, 256)
    const float* __restrict__ Wk,     // (2, 256)
    const float* __restrict__ Wv,     // (2, 256)
    float*       __restrict__ last)   // (BN, 256)
{
    const int bn  = blockIdx.x;
    const int tid = threadIdx.x;          // c = h*32 + d
    const int d   = tid & 31;
    const int j   = d >> 1;               // rope pair index 0..15
    const bool even = (d & 1) == 0;

    __shared__ float cs_s[LSEQ * 16];
    __shared__ float sn_s[LSEQ * 16];

    const float* tb = t + bn * LSEQ;
    // Precompute cos/sin for all (m, j). inv_freq[j] = 10000^(-2j/32)
    for (int i = tid; i < LSEQ * 16; i += 256) {
        int m  = i >> 4;
        int jj = i & 15;
        float invf = exp2f(-(float)jj * 0.8304820237218407f); // j/16*log2(1e4)
        float ang = tb[m] * invf;
        float sv, cv;
        sincosf(ang, &sv, &cv);
        cs_s[i] = cv;
        sn_s[i] = sv;
    }
    __syncthreads();

    const int ce = tid & ~1;   // even channel of my rope pair
    const int co = ce + 1;

    const float e0 = emb[0], e1 = emb[1];

    // q at position 0 (uses t[bn,0] via cs_s[j], sn_s[j])
    float qa = e0 * Wq[ce] + e1 * Wq[256 + ce];
    float qb = e0 * Wq[co] + e1 * Wq[256 + co];
    float c0 = cs_s[j], s0 = sn_s[j];
    float q  = even ? (qa * c0 - qb * s0) : (qa * s0 + qb * c0);
    q *= 0.17677669529663687f;  // 1/sqrt(QK_DIM)

    // Loop-invariant weights
    const float wk0e = Wk[ce],       wk1e = Wk[256 + ce];
    const float wk0o = Wk[co],       wk1o = Wk[256 + co];
    const float wv0  = Wv[tid],      wv1  = Wv[256 + tid];

    const int*   mb = mask + bn * LSEQ;
    const float* xb = x + bn * (PLEN * 2);
    const int mask0 = mb[0];

    float run_max = -1e30f, run_sum = 0.f, acc = 0.f;

    for (int m = 0; m < LSEQ; ++m) {
        int mk = mb[m];
        // If mask0==0, every score is NEG -> uniform softmax over ALL m.
        bool inc = (mask0 == 0) || (mk != 0);
        if (!inc) continue;   // exp(NEG - max) == 0 exactly in fp32

        float x0, x1;
        if (m == 0) { x0 = e0; x1 = e1; }
        else        { x0 = xb[(m - 1) * 2]; x1 = xb[(m - 1) * 2 + 1]; }

        float cs = cs_s[m * 16 + j], sn = sn_s[m * 16 + j];
        float ka = x0 * wk0e + x1 * wk1e;
        float kb = x0 * wk0o + x1 * wk1o;
        float k  = even ? (ka * cs - kb * sn) : (ka * sn + kb * cs);
        float v  = x0 * wv0 + x1 * wv1;

        float p = q * k;
        // reduce over the 32 lanes of this head (head = 32 aligned lanes)
        p += __shfl_xor(p, 16, 64);
        p += __shfl_xor(p, 8, 64);
        p += __shfl_xor(p, 4, 64);
        p += __shfl_xor(p, 2, 64);
        p += __shfl_xor(p, 1, 64);

        float s = (mask0 == 0) ? 0.f : p;
        float nm = fmaxf(run_max, s);
        float alpha = __expf(run_max - nm);   // run_max=-1e30 -> alpha = 0
        float w     = __expf(s - nm);
        run_sum = run_sum * alpha + w;
        acc     = acc * alpha + w * v;
        run_max = nm;
    }

    last[bn * 256 + tid] = acc / run_sum;
}

// -------------------------------------------------------------------------
// Kernel 2: LayerNorm -> FF1(256->1024)+ReLU -> FF2(1024->256) -> +residual
//           -> Wo (256->256). 4 rows per block, 256 threads.
// 256 blocks -> weight traffic 256 x 2.25MB from L2.
// -------------------------------------------------------------------------
__global__ __launch_bounds__(256) void mlp_kernel(
    const float* __restrict__ last,  // (BN, 256)
    const float* __restrict__ ln_g,  // (256,)
    const float* __restrict__ ln_b,  // (256,)
    const float* __restrict__ W1,    // (256, 1024)
    const float* __restrict__ b1,    // (1024,)
    const float* __restrict__ W2,    // (1024, 256)
    const float* __restrict__ b2,    // (256,)
    const float* __restrict__ Wo,    // (256, 256)
    float*       __restrict__ out)   // (BN, 256)
{
    const int tid = threadIdx.x;
    const int r0  = blockIdx.x * 4;

    __shared__ float h_s[4][INNER];    // post-LN
    __shared__ float y_s[4][HID];      // post-ReLU hidden
    __shared__ float r_s[4][INNER];    // residual sum
    __shared__ float red_s[4][4][2];   // [row][wave][sum, sumsq]

    float xr[4];
#pragma unroll
    for (int r = 0; r < 4; ++r) xr[r] = last[(r0 + r) * INNER + tid];

    // ---- LayerNorm stats (per-row mean/var over 256 channels) ----
    float s1[4], s2[4];
#pragma unroll
    for (int r = 0; r < 4; ++r) { s1[r] = xr[r]; s2[r] = xr[r] * xr[r]; }
#pragma unroll
    for (int off = 32; off >= 1; off >>= 1) {
#pragma unroll
        for (int r = 0; r < 4; ++r) {
            s1[r] += __shfl_xor(s1[r], off, 64);
            s2[r] += __shfl_xor(s2[r], off, 64);
        }
    }
    const int wave = tid >> 6;
    if ((tid & 63) == 0) {
#pragma unroll
        for (int r = 0; r < 4; ++r) {
            red_s[r][wave][0] = s1[r];
            red_s[r][wave][1] = s2[r];
        }
    }
    __syncthreads();

    const float g  = ln_g[tid];
    const float bb = ln_b[tid];
#pragma unroll
    for (int r = 0; r < 4; ++r) {
        float t1 = red_s[r][0][0] + red_s[r][1][0] + red_s[r][2][0] + red_s[r][3][0];
        float t2 = red_s[r][0][1] + red_s[r][1][1] + red_s[r][2][1] + red_s[r][3][1];
        float mu  = t1 * (1.f / 256.f);
        float var = t2 * (1.f / 256.f) - mu * mu;
        float rs  = rsqrtf(var + 1e-5f);
        h_s[r][tid] = (xr[r] - mu) * rs * g + bb;
    }
    __syncthreads();

    // ---- FF1: (4 rows) x (256 -> 1024), thread owns j = tid + 256k ----
    float a1[4][4];
#pragma unroll
    for (int k = 0; k < 4; ++k) {
        float bv = b1[tid + 256 * k];
#pragma unroll
        for (int r = 0; r < 4; ++r) a1[r][k] = bv;
    }
#pragma unroll 4
    for (int c = 0; c < 256; ++c) {
        float w0 = W1[c * HID + tid];
        float w1 = W1[c * HID + tid + 256];
        float w2 = W1[c * HID + tid + 512];
        float w3 = W1[c * HID + tid + 768];
#pragma unroll
        for (int r = 0; r < 4; ++r) {
            float hv = h_s[r][c];
            a1[r][0] = fmaf(hv, w0, a1[r][0]);
            a1[r][1] = fmaf(hv, w1, a1[r][1]);
            a1[r][2] = fmaf(hv, w2, a1[r][2]);
            a1[r][3] = fmaf(hv, w3, a1[r][3]);
        }
    }
#pragma unroll
    for (int r = 0; r < 4; ++r)
#pragma unroll
        for (int k = 0; k < 4; ++k)
            y_s[r][tid + 256 * k] = fmaxf(a1[r][k], 0.f);
    __syncthreads();

    // ---- FF2: (4 rows) x (1024 -> 256), thread owns out channel tid ----
    float a2[4];
    {
        float bv = b2[tid];
#pragma unroll
        for (int r = 0; r < 4; ++r) a2[r] = bv;
    }
#pragma unroll 4
    for (int jj = 0; jj < HID; ++jj) {
        float w = W2[jj * INNER + tid];
#pragma unroll
        for (int r = 0; r < 4; ++r) a2[r] = fmaf(y_s[r][jj], w, a2[r]);
    }
#pragma unroll
    for (int r = 0; r < 4; ++r) r_s[r][tid] = xr[r] + a2[r];
    __syncthreads();

    // ---- Wo: (4 rows) x (256 -> 256) ----
    float ao[4] = {0.f, 0.f, 0.f, 0.f};
#pragma unroll 4
    for (int c = 0; c < 256; ++c) {
        float w = Wo[c * INNER + tid];
#pragma unroll
        for (int r = 0; r < 4; ++r) ao[r] = fmaf(r_s[r][c], w, ao[r]);
    }
#pragma unroll
    for (int r = 0; r < 4; ++r) out[(r0 + r) * INNER + tid] = ao[r];
}

// -------------------------------------------------------------------------
extern "C" void kernel_launch(void* const* d_in, const int* in_sizes, int n_in,
                              void* d_out, int out_size, void* d_ws, size_t ws_size,
                              hipStream_t stream) {
    const float* x    = (const float*)d_in[0];
    const float* t    = (const float*)d_in[1];
    const int*   mask = (const int*)  d_in[2];
    const float* emb  = (const float*)d_in[3];
    const float* Wq   = (const float*)d_in[4];
    const float* Wk   = (const float*)d_in[5];
    const float* Wv   = (const float*)d_in[6];
    const float* Wo   = (const float*)d_in[7];
    const float* ln_g = (const float*)d_in[8];
    const float* ln_b = (const float*)d_in[9];
    const float* W1   = (const float*)d_in[10];
    const float* b1   = (const float*)d_in[11];
    const float* W2   = (const float*)d_in[12];
    const float* b2   = (const float*)d_in[13];
    float* out = (float*)d_out;

    const int BN = in_sizes[1] / LSEQ;   // t is (BN, 129) -> 1024

    float* last_ws = (float*)d_ws;       // BN * 256 floats = 1 MB

    attn_kernel<<<BN, 256, 0, stream>>>(x, t, mask, emb, Wq, Wk, Wv, last_ws);
    mlp_kernel<<<BN / 4, 256, 0, stream>>>(last_ws, ln_g, ln_b, W1, b1, W2, b2,
                                           Wo, out);
}

// Round 2
// 151.515 us; speedup vs baseline: 1.5133x; 1.5133x over previous
//
#include <hip/hip_runtime.h>
#include <math.h>

// Problem constants (from reference)
#define LSEQ   129      // PL + 1
#define PLEN   128
#define NHEAD  8
#define DHEAD  32
#define INNER  256      // NHEAD * V_DIM
#define HID    1024     // 4 * INNER

// -------------------------------------------------------------------------
// Kernel 1: QKV projection (rank-2) + RoPE + single-query (l=0) attention.
// One block per bn (B*PN = 1024), 256 threads = one channel c = h*32+d each.
// Online softmax; K/V recomputed on the fly (2 FMAs each). Writes last[bn,c].
// -------------------------------------------------------------------------
__global__ __launch_bounds__(256) void attn_kernel(
    const float* __restrict__ x,      // (BN, PL, 2)
    const float* __restrict__ t,      // (BN, L)
    const int*   __restrict__ mask,   // (BN, L)
    const float* __restrict__ emb,    // (2,)
    const float* __restrict__ Wq,     // (2, 256)
    const float* __restrict__ Wk,     // (2, 256)
    const float* __restrict__ Wv,     // (2, 256)
    float*       __restrict__ last)   // (BN, 256)
{
    const int bn  = blockIdx.x;
    const int tid = threadIdx.x;          // c = h*32 + d
    const int d   = tid & 31;
    const int j   = d >> 1;               // rope pair index 0..15
    const bool even = (d & 1) == 0;

    __shared__ float cs_s[LSEQ * 16];
    __shared__ float sn_s[LSEQ * 16];

    const float* tb = t + bn * LSEQ;
    // Precompute cos/sin for all (m, j). inv_freq[j] = 10000^(-2j/32)
    for (int i = tid; i < LSEQ * 16; i += 256) {
        int m  = i >> 4;
        int jj = i & 15;
        float invf = exp2f(-(float)jj * 0.8304820237218407f); // j/16*log2(1e4)
        float ang = tb[m] * invf;
        float sv, cv;
        sincosf(ang, &sv, &cv);
        cs_s[i] = cv;
        sn_s[i] = sv;
    }
    __syncthreads();

    const int ce = tid & ~1;   // even channel of my rope pair
    const int co = ce + 1;

    const float e0 = emb[0], e1 = emb[1];

    // q at position 0 (uses t[bn,0] via cs_s[j], sn_s[j])
    float qa = e0 * Wq[ce] + e1 * Wq[256 + ce];
    float qb = e0 * Wq[co] + e1 * Wq[256 + co];
    float c0 = cs_s[j], s0 = sn_s[j];
    float q  = even ? (qa * c0 - qb * s0) : (qa * s0 + qb * c0);
    q *= 0.17677669529663687f;  // 1/sqrt(QK_DIM)

    // Loop-invariant weights
    const float wk0e = Wk[ce],       wk1e = Wk[256 + ce];
    const float wk0o = Wk[co],       wk1o = Wk[256 + co];
    const float wv0  = Wv[tid],      wv1  = Wv[256 + tid];

    const int*   mb = mask + bn * LSEQ;
    const float* xb = x + bn * (PLEN * 2);
    const int mask0 = mb[0];

    float run_max = -1e30f, run_sum = 0.f, acc = 0.f;

    for (int m = 0; m < LSEQ; ++m) {
        int mk = mb[m];
        // If mask0==0, every score is NEG -> uniform softmax over ALL m.
        bool inc = (mask0 == 0) || (mk != 0);
        if (!inc) continue;   // exp(NEG - max) == 0 exactly in fp32

        float x0, x1;
        if (m == 0) { x0 = e0; x1 = e1; }
        else        { x0 = xb[(m - 1) * 2]; x1 = xb[(m - 1) * 2 + 1]; }

        float cs = cs_s[m * 16 + j], sn = sn_s[m * 16 + j];
        float ka = x0 * wk0e + x1 * wk1e;
        float kb = x0 * wk0o + x1 * wk1o;
        float k  = even ? (ka * cs - kb * sn) : (ka * sn + kb * cs);
        float v  = x0 * wv0 + x1 * wv1;

        float p = q * k;
        // reduce over the 32 lanes of this head (head = 32 aligned lanes)
        p += __shfl_xor(p, 16, 64);
        p += __shfl_xor(p, 8, 64);
        p += __shfl_xor(p, 4, 64);
        p += __shfl_xor(p, 2, 64);
        p += __shfl_xor(p, 1, 64);

        float s = (mask0 == 0) ? 0.f : p;
        float nm = fmaxf(run_max, s);
        float alpha = __expf(run_max - nm);   // run_max=-1e30 -> alpha = 0
        float w     = __expf(s - nm);
        run_sum = run_sum * alpha + w;
        acc     = acc * alpha + w * v;
        run_max = nm;
    }

    last[bn * 256 + tid] = acc / run_sum;
}

// -------------------------------------------------------------------------
// Kernel 2: LayerNorm -> FF1(256->1024)+ReLU -> FF2(1024->256) -> +residual
//           -> Wo (256->256). 4 rows per block, 1024 threads (16 waves/CU,
//           4 waves/SIMD) so L2 latency is hidden by TLP. 256 blocks keeps
//           L2 weight traffic at 256 x 2.25 MB = 576 MB (~17 us floor).
// -------------------------------------------------------------------------
__global__ __launch_bounds__(1024) void mlp_kernel(
    const float* __restrict__ last,  // (BN, 256)
    const float* __restrict__ ln_g,  // (256,)
    const float* __restrict__ ln_b,  // (256,)
    const float* __restrict__ W1,    // (256, 1024)
    const float* __restrict__ b1,    // (1024,)
    const float* __restrict__ W2,    // (1024, 256)
    const float* __restrict__ b2,    // (256,)
    const float* __restrict__ Wo,    // (256, 256)
    float*       __restrict__ out)   // (BN, 256)
{
    const int tid = threadIdx.x;      // 0..1023
    const int r0  = blockIdx.x * 4;
    const int rg  = tid >> 8;         // 0..3: row (LN phase) / k-chunk (FF2,Wo)
    const int ch  = tid & 255;        // channel / out-column

    __shared__ float h_s[4][INNER];     // post-LN            4 KB
    __shared__ float x_s[4][INNER];     // raw last rows      4 KB
    __shared__ float y_s[4][HID];       // post-ReLU hidden  16 KB
    __shared__ float p_s[4][4][INNER];  // [kc][row][col]    16 KB
    __shared__ float r_s[4][INNER];     // residual sum       4 KB
    __shared__ float red_s[16][2];      // per-wave LN partials

    // ---- load 4 rows: thread (rg, ch) owns last[r0+rg, ch] ----
    float xv = last[(r0 + rg) * INNER + ch];
    x_s[rg][ch] = xv;

    // ---- LayerNorm stats: wave-level reduce (each row = waves 4rg..4rg+3) --
    float s1 = xv, s2 = xv * xv;
#pragma unroll
    for (int off = 32; off >= 1; off >>= 1) {
        s1 += __shfl_xor(s1, off, 64);
        s2 += __shfl_xor(s2, off, 64);
    }
    const int wave = tid >> 6;
    if ((tid & 63) == 0) { red_s[wave][0] = s1; red_s[wave][1] = s2; }
    __syncthreads();

    {
        float t1 = red_s[4 * rg + 0][0] + red_s[4 * rg + 1][0] +
                   red_s[4 * rg + 2][0] + red_s[4 * rg + 3][0];
        float t2 = red_s[4 * rg + 0][1] + red_s[4 * rg + 1][1] +
                   red_s[4 * rg + 2][1] + red_s[4 * rg + 3][1];
        float mu  = t1 * (1.f / 256.f);
        float var = t2 * (1.f / 256.f) - mu * mu;
        float rs  = rsqrtf(var + 1e-5f);
        h_s[rg][ch] = (xv - mu) * rs * ln_g[ch] + ln_b[ch];
    }
    __syncthreads();

    // ---- FF1: thread owns hidden col jj = tid; 4 row-accumulators ----
    {
        float a0, a1v, a2v, a3;
        a0 = a1v = a2v = a3 = b1[tid];
        const float* w = W1 + tid;
#pragma unroll 8
        for (int c = 0; c < INNER; ++c) {
            float wv = w[c * HID];
            a0  = fmaf(h_s[0][c], wv, a0);
            a1v = fmaf(h_s[1][c], wv, a1v);
            a2v = fmaf(h_s[2][c], wv, a2v);
            a3  = fmaf(h_s[3][c], wv, a3);
        }
        y_s[0][tid] = fmaxf(a0, 0.f);
        y_s[1][tid] = fmaxf(a1v, 0.f);
        y_s[2][tid] = fmaxf(a2v, 0.f);
        y_s[3][tid] = fmaxf(a3, 0.f);
    }
    __syncthreads();

    // ---- FF2: thread (kc=rg, col=ch) does K-chunk of 256; 4 rows ----
    {
        float a0 = 0.f, a1v = 0.f, a2v = 0.f, a3 = 0.f;
        const int cbase = rg * 256;
        const float* w = W2 + cbase * INNER + ch;
#pragma unroll 8
        for (int i = 0; i < 256; ++i) {
            float wv = w[i * INNER];
            int c = cbase + i;
            a0  = fmaf(y_s[0][c], wv, a0);
            a1v = fmaf(y_s[1][c], wv, a1v);
            a2v = fmaf(y_s[2][c], wv, a2v);
            a3  = fmaf(y_s[3][c], wv, a3);
        }
        p_s[rg][0][ch] = a0;
        p_s[rg][1][ch] = a1v;
        p_s[rg][2][ch] = a2v;
        p_s[rg][3][ch] = a3;
    }
    __syncthreads();

    // ---- combine FF2 partials + bias + residual: thread (row=rg, col=ch) --
    r_s[rg][ch] = x_s[rg][ch] + b2[ch] +
                  p_s[0][rg][ch] + p_s[1][rg][ch] +
                  p_s[2][rg][ch] + p_s[3][rg][ch];
    __syncthreads();

    // ---- Wo: thread (kc=rg, col=ch) does K-chunk of 64; 4 rows ----
    {
        float a0 = 0.f, a1v = 0.f, a2v = 0.f, a3 = 0.f;
        const int cbase = rg * 64;
        const float* w = Wo + cbase * INNER + ch;
#pragma unroll 8
        for (int i = 0; i < 64; ++i) {
            float wv = w[i * INNER];
            int c = cbase + i;
            a0  = fmaf(r_s[0][c], wv, a0);
            a1v = fmaf(r_s[1][c], wv, a1v);
            a2v = fmaf(r_s[2][c], wv, a2v);
            a3  = fmaf(r_s[3][c], wv, a3);
        }
        p_s[rg][0][ch] = a0;
        p_s[rg][1][ch] = a1v;
        p_s[rg][2][ch] = a2v;
        p_s[rg][3][ch] = a3;
    }
    __syncthreads();

    // ---- final combine + store: thread (row=rg, col=ch) ----
    out[(r0 + rg) * INNER + ch] = p_s[0][rg][ch] + p_s[1][rg][ch] +
                                  p_s[2][rg][ch] + p_s[3][rg][ch];
}

// -------------------------------------------------------------------------
extern "C" void kernel_launch(void* const* d_in, const int* in_sizes, int n_in,
                              void* d_out, int out_size, void* d_ws, size_t ws_size,
                              hipStream_t stream) {
    const float* x    = (const float*)d_in[0];
    const float* t    = (const float*)d_in[1];
    const int*   mask = (const int*)  d_in[2];
    const float* emb  = (const float*)d_in[3];
    const float* Wq   = (const float*)d_in[4];
    const float* Wk   = (const float*)d_in[5];
    const float* Wv   = (const float*)d_in[6];
    const float* Wo   = (const float*)d_in[7];
    const float* ln_g = (const float*)d_in[8];
    const float* ln_b = (const float*)d_in[9];
    const float* W1   = (const float*)d_in[10];
    const float* b1   = (const float*)d_in[11];
    const float* W2   = (const float*)d_in[12];
    const float* b2   = (const float*)d_in[13];
    float* out = (float*)d_out;

    const int BN = in_sizes[1] / LSEQ;   // t is (BN, 129) -> 1024

    float* last_ws = (float*)d_ws;       // BN * 256 floats = 1 MB

    attn_kernel<<<BN, 256, 0, stream>>>(x, t, mask, emb, Wq, Wk, Wv, last_ws);
    mlp_kernel<<<BN / 4, 1024, 0, stream>>>(last_ws, ln_g, ln_b, W1, b1, W2, b2,
                                            Wo, out);
}

// Round 3
// 138.577 us; speedup vs baseline: 1.6546x; 1.0934x over previous
//
#include <hip/hip_runtime.h>
#include <math.h>

// Problem constants (from reference)
#define LSEQ   129      // PL + 1
#define PLEN   128
#define NHEAD  8
#define DHEAD  32
#define INNER  256      // NHEAD * V_DIM
#define HID    1024     // 4 * INNER

typedef _Float16 h2 __attribute__((ext_vector_type(2)));

__device__ __forceinline__ float dot2(h2 a, h2 b, float c) {
#if __has_builtin(__builtin_amdgcn_fdot2)
    return __builtin_amdgcn_fdot2(a, b, c, false);   // v_dot2_f32_f16
#else
    return c + (float)a.x * (float)b.x + (float)a.y * (float)b.y;
#endif
}

__device__ __forceinline__ h2 pack2(float a, float b) {
    h2 v; v.x = (_Float16)a; v.y = (_Float16)b; return v;
}

// -------------------------------------------------------------------------
// Kernel 0: pack fp32 weights into K-paired fp16 half2 in workspace.
//   W1p[c2*1024+j] = (W1[2c2][j], W1[2c2+1][j])   c2<128
//   W2p[c2*256 +o] = (W2[2c2][o], W2[2c2+1][o])   c2<512
//   Wop[c2*256 +o] = (Wo[2c2][o], Wo[2c2+1][o])   c2<128
// -------------------------------------------------------------------------
__global__ __launch_bounds__(256) void convert_kernel(
    const float* __restrict__ W1, const float* __restrict__ W2,
    const float* __restrict__ Wo,
    h2* __restrict__ W1p, h2* __restrict__ W2p, h2* __restrict__ Wop)
{
    int idx = blockIdx.x * 256 + threadIdx.x;
    if (idx < 131072) {                       // W1: 128 x 1024
        int c2 = idx >> 10, jc = idx & 1023;
        W1p[idx] = pack2(W1[(2 * c2) * HID + jc], W1[(2 * c2 + 1) * HID + jc]);
    } else if (idx < 262144) {                // W2: 512 x 256
        int l = idx - 131072;
        int c2 = l >> 8, jc = l & 255;
        W2p[l] = pack2(W2[(2 * c2) * INNER + jc], W2[(2 * c2 + 1) * INNER + jc]);
    } else if (idx < 294912) {                // Wo: 128 x 256
        int l = idx - 262144;
        int c2 = l >> 8, jc = l & 255;
        Wop[l] = pack2(Wo[(2 * c2) * INNER + jc], Wo[(2 * c2 + 1) * INNER + jc]);
    }
}

// -------------------------------------------------------------------------
// Kernel 1: QKV projection (rank-2) + RoPE + single-query (l=0) attention.
// 1024 threads = 4 m-chunk groups x 256 channels. Each group runs online
// softmax over ~32 of the 129 positions (serial chain 129 -> 33), states
// merged through LDS. K/V recomputed on the fly (rank-2, 2 FMAs each).
// -------------------------------------------------------------------------
__global__ __launch_bounds__(1024) void attn_kernel(
    const float* __restrict__ x,      // (BN, PL, 2)
    const float* __restrict__ t,      // (BN, L)
    const int*   __restrict__ mask,   // (BN, L)
    const float* __restrict__ emb,    // (2,)
    const float* __restrict__ Wq,     // (2, 256)
    const float* __restrict__ Wk,     // (2, 256)
    const float* __restrict__ Wv,     // (2, 256)
    float*       __restrict__ last)   // (BN, 256)
{
    const int bn  = blockIdx.x;
    const int tid = threadIdx.x;
    const int g   = tid >> 8;             // m-chunk group 0..3
    const int c   = tid & 255;            // channel = h*32+d
    const int d   = c & 31;
    const int j   = d >> 1;               // rope pair index 0..15
    const bool even = (d & 1) == 0;

    __shared__ float cs_s[LSEQ * 16];
    __shared__ float sn_s[LSEQ * 16];
    __shared__ float acc_s[4][256];
    __shared__ float mx_s[4][NHEAD];
    __shared__ float sum_s[4][NHEAD];

    const float* tb = t + bn * LSEQ;
    for (int i = tid; i < LSEQ * 16; i += 1024) {
        int m  = i >> 4;
        int jj = i & 15;
        float invf = exp2f(-(float)jj * 0.8304820237218407f); // j/16*log2(1e4)
        float sv, cv;
        sincosf(tb[m] * invf, &sv, &cv);
        cs_s[i] = cv;
        sn_s[i] = sv;
    }
    __syncthreads();

    const int ce = c & ~1;
    const int co = ce + 1;
    const float e0 = emb[0], e1 = emb[1];

    // q at position 0
    float qa = e0 * Wq[ce] + e1 * Wq[256 + ce];
    float qb = e0 * Wq[co] + e1 * Wq[256 + co];
    float c0 = cs_s[j], s0 = sn_s[j];
    float q  = even ? (qa * c0 - qb * s0) : (qa * s0 + qb * c0);
    q *= 0.17677669529663687f;  // 1/sqrt(QK_DIM)

    const float wk0e = Wk[ce],  wk1e = Wk[256 + ce];
    const float wk0o = Wk[co],  wk1o = Wk[256 + co];
    const float wv0  = Wv[c],   wv1  = Wv[256 + c];

    const int*   mb = mask + bn * LSEQ;
    const float* xb = x + bn * (PLEN * 2);
    const int mask0 = mb[0];

    // chunk bounds: g0:[0,33) g1:[33,65) g2:[65,97) g3:[97,129)
    const int mstart = (g == 0) ? 0 : (32 * g + 1);
    const int mend   = 32 * g + 33;

    float run_max = -1e30f, run_sum = 0.f, acc = 0.f;

    for (int m = mstart; m < mend; ++m) {
        int mk = mb[m];
        bool inc = (mask0 == 0) || (mk != 0);
        if (!inc) continue;   // exp(NEG - max) == 0 exactly in fp32

        float x0, x1;
        if (m == 0) { x0 = e0; x1 = e1; }
        else        { x0 = xb[(m - 1) * 2]; x1 = xb[(m - 1) * 2 + 1]; }

        float cs = cs_s[m * 16 + j], sn = sn_s[m * 16 + j];
        float ka = x0 * wk0e + x1 * wk1e;
        float kb = x0 * wk0o + x1 * wk1o;
        float k  = even ? (ka * cs - kb * sn) : (ka * sn + kb * cs);
        float v  = x0 * wv0 + x1 * wv1;

        float p = q * k;
        p += __shfl_xor(p, 16, 64);
        p += __shfl_xor(p, 8, 64);
        p += __shfl_xor(p, 4, 64);
        p += __shfl_xor(p, 2, 64);
        p += __shfl_xor(p, 1, 64);

        float s = (mask0 == 0) ? 0.f : p;
        float nm = fmaxf(run_max, s);
        float alpha = __expf(run_max - nm);
        float w     = __expf(s - nm);
        run_sum = run_sum * alpha + w;
        acc     = acc * alpha + w * v;
        run_max = nm;
    }

    acc_s[g][c] = acc;
    if (d == 0) { mx_s[g][c >> 5] = run_max; sum_s[g][c >> 5] = run_sum; }
    __syncthreads();

    // merge 4 chunk states (empty chunk: mx=-1e30 -> exp -> 0, sum=0, acc=0)
    if (tid < 256) {
        int h = tid >> 5;
        float M = fmaxf(fmaxf(mx_s[0][h], mx_s[1][h]),
                        fmaxf(mx_s[2][h], mx_s[3][h]));
        float num = 0.f, den = 0.f;
#pragma unroll
        for (int gg = 0; gg < 4; ++gg) {
            float f = __expf(mx_s[gg][h] - M);
            den += sum_s[gg][h] * f;
            num += acc_s[gg][tid] * f;
        }
        last[bn * 256 + tid] = num / den;
    }
}

// -------------------------------------------------------------------------
// Kernel 2: LayerNorm -> FF1(256->1024)+ReLU -> FF2(1024->256) -> +residual
//           -> Wo (256->256). 4 rows/block, 1024 threads. fp16 packed
//           weights + v_dot2_f32_f16 (fp32 accumulate): halves L2 bytes
//           (576->288 MB) and VALU instructions vs fp32.
// -------------------------------------------------------------------------
__global__ __launch_bounds__(1024) void mlp_kernel(
    const float* __restrict__ last,  // (BN, 256)
    const float* __restrict__ ln_g,  // (256,)
    const float* __restrict__ ln_b,  // (256,)
    const h2*    __restrict__ W1p,   // (128, 1024) K-paired
    const float* __restrict__ b1,    // (1024,)
    const h2*    __restrict__ W2p,   // (512, 256)  K-paired
    const float* __restrict__ b2,    // (256,)
    const h2*    __restrict__ Wop,   // (128, 256)  K-paired
    float*       __restrict__ out)   // (BN, 256)
{
    const int tid = threadIdx.x;      // 0..1023
    const int r0  = blockIdx.x * 4;
    const int rg  = tid >> 8;         // row (LN) / k-chunk (FF2, Wo)
    const int ch  = tid & 255;

    __shared__ float x_s[4][INNER];     //  4 KB raw rows
    __shared__ h2    h2_s[4][128];      //  2 KB post-LN (fp16 pairs)
    __shared__ h2    y2_s[4][512];      //  8 KB post-ReLU hidden
    __shared__ float p_s[4][4][INNER];  // 16 KB partials [kc][row][col]
    __shared__ h2    r2_s[4][128];      //  2 KB residual (fp16 pairs)
    __shared__ float red_s[16][2];

    // ---- load 4 rows ----
    float xv = last[(r0 + rg) * INNER + ch];
    x_s[rg][ch] = xv;

    // ---- LayerNorm (row rg spans waves 4rg..4rg+3) ----
    float s1 = xv, s2 = xv * xv;
#pragma unroll
    for (int off = 32; off >= 1; off >>= 1) {
        s1 += __shfl_xor(s1, off, 64);
        s2 += __shfl_xor(s2, off, 64);
    }
    const int wave = tid >> 6;
    if ((tid & 63) == 0) { red_s[wave][0] = s1; red_s[wave][1] = s2; }
    __syncthreads();

    {
        float t1 = red_s[4 * rg + 0][0] + red_s[4 * rg + 1][0] +
                   red_s[4 * rg + 2][0] + red_s[4 * rg + 3][0];
        float t2 = red_s[4 * rg + 0][1] + red_s[4 * rg + 1][1] +
                   red_s[4 * rg + 2][1] + red_s[4 * rg + 3][1];
        float mu  = t1 * (1.f / 256.f);
        float var = t2 * (1.f / 256.f) - mu * mu;
        float rs  = rsqrtf(var + 1e-5f);
        float hv  = (xv - mu) * rs * ln_g[ch] + ln_b[ch];
        float ho  = __shfl_xor(hv, 1, 64);          // neighbor channel
        if ((ch & 1) == 0) h2_s[rg][ch >> 1] = pack2(hv, ho);
    }
    __syncthreads();

    // ---- FF1: thread owns hidden col tid; 4 row-accumulators ----
    {
        float a0, a1v, a2v, a3;
        a0 = a1v = a2v = a3 = b1[tid];
        const h2* w = W1p + tid;
#pragma unroll 16
        for (int c2 = 0; c2 < 128; ++c2) {
            h2 wv = w[c2 * HID];
            a0  = dot2(h2_s[0][c2], wv, a0);
            a1v = dot2(h2_s[1][c2], wv, a1v);
            a2v = dot2(h2_s[2][c2], wv, a2v);
            a3  = dot2(h2_s[3][c2], wv, a3);
        }
        a0 = fmaxf(a0, 0.f); a1v = fmaxf(a1v, 0.f);
        a2v = fmaxf(a2v, 0.f); a3 = fmaxf(a3, 0.f);
        float o0 = __shfl_xor(a0, 1, 64);
        float o1 = __shfl_xor(a1v, 1, 64);
        float o2 = __shfl_xor(a2v, 1, 64);
        float o3 = __shfl_xor(a3, 1, 64);
        if ((tid & 1) == 0) {
            int p = tid >> 1;
            y2_s[0][p] = pack2(a0, o0);
            y2_s[1][p] = pack2(a1v, o1);
            y2_s[2][p] = pack2(a2v, o2);
            y2_s[3][p] = pack2(a3, o3);
        }
    }
    __syncthreads();

    // ---- FF2: thread (kc=rg, col=ch), K-chunk of 128 pairs; 4 rows ----
    {
        float a0 = 0.f, a1v = 0.f, a2v = 0.f, a3 = 0.f;
        const h2* w = W2p + rg * 128 * INNER + ch;
#pragma unroll 16
        for (int i = 0; i < 128; ++i) {
            h2 wv = w[i * INNER];
            int c2 = rg * 128 + i;
            a0  = dot2(y2_s[0][c2], wv, a0);
            a1v = dot2(y2_s[1][c2], wv, a1v);
            a2v = dot2(y2_s[2][c2], wv, a2v);
            a3  = dot2(y2_s[3][c2], wv, a3);
        }
        p_s[rg][0][ch] = a0;
        p_s[rg][1][ch] = a1v;
        p_s[rg][2][ch] = a2v;
        p_s[rg][3][ch] = a3;
    }
    __syncthreads();

    // ---- combine + bias + residual; repack to fp16 pairs ----
    {
        float rv = x_s[rg][ch] + b2[ch] +
                   p_s[0][rg][ch] + p_s[1][rg][ch] +
                   p_s[2][rg][ch] + p_s[3][rg][ch];
        float ro = __shfl_xor(rv, 1, 64);
        if ((ch & 1) == 0) r2_s[rg][ch >> 1] = pack2(rv, ro);
    }
    __syncthreads();

    // ---- Wo: thread (kc=rg, col=ch), K-chunk of 32 pairs; 4 rows ----
    {
        float a0 = 0.f, a1v = 0.f, a2v = 0.f, a3 = 0.f;
        const h2* w = Wop + rg * 32 * INNER + ch;
#pragma unroll
        for (int i = 0; i < 32; ++i) {
            h2 wv = w[i * INNER];
            int c2 = rg * 32 + i;
            a0  = dot2(r2_s[0][c2], wv, a0);
            a1v = dot2(r2_s[1][c2], wv, a1v);
            a2v = dot2(r2_s[2][c2], wv, a2v);
            a3  = dot2(r2_s[3][c2], wv, a3);
        }
        p_s[rg][0][ch] = a0;
        p_s[rg][1][ch] = a1v;
        p_s[rg][2][ch] = a2v;
        p_s[rg][3][ch] = a3;
    }
    __syncthreads();

    out[(r0 + rg) * INNER + ch] = p_s[0][rg][ch] + p_s[1][rg][ch] +
                                  p_s[2][rg][ch] + p_s[3][rg][ch];
}

// -------------------------------------------------------------------------
extern "C" void kernel_launch(void* const* d_in, const int* in_sizes, int n_in,
                              void* d_out, int out_size, void* d_ws, size_t ws_size,
                              hipStream_t stream) {
    const float* x    = (const float*)d_in[0];
    const float* t    = (const float*)d_in[1];
    const int*   mask = (const int*)  d_in[2];
    const float* emb  = (const float*)d_in[3];
    const float* Wq   = (const float*)d_in[4];
    const float* Wk   = (const float*)d_in[5];
    const float* Wv   = (const float*)d_in[6];
    const float* Wo   = (const float*)d_in[7];
    const float* ln_g = (const float*)d_in[8];
    const float* ln_b = (const float*)d_in[9];
    const float* W1   = (const float*)d_in[10];
    const float* b1   = (const float*)d_in[11];
    const float* W2   = (const float*)d_in[12];
    const float* b2   = (const float*)d_in[13];
    float* out = (float*)d_out;

    const int BN = in_sizes[1] / LSEQ;   // 1024

    char* ws = (char*)d_ws;
    float* last_ws = (float*)ws;                      // 1 MB
    h2* W1p = (h2*)(ws + (1u << 20));                 // 0.5 MB
    h2* W2p = (h2*)(ws + (1u << 20) + (512u << 10));  // 0.5 MB
    h2* Wop = (h2*)(ws + (2u << 20));                 // 0.125 MB

    convert_kernel<<<1152, 256, 0, stream>>>(W1, W2, Wo, W1p, W2p, Wop);
    attn_kernel<<<BN, 1024, 0, stream>>>(x, t, mask, emb, Wq, Wk, Wv, last_ws);
    mlp_kernel<<<BN / 4, 1024, 0, stream>>>(last_ws, ln_g, ln_b, W1p, b1,
                                            W2p, b2, Wop, out);
}

// Round 4
// 111.804 us; speedup vs baseline: 2.0508x; 1.2395x over previous
//
#include <hip/hip_runtime.h>
#include <math.h>

// Problem constants (from reference)
#define LSEQ   129      // PL + 1
#define PLEN   128
#define NHEAD  8
#define DHEAD  32
#define INNER  256      // NHEAD * V_DIM
#define HID    1024     // 4 * INNER

typedef _Float16 h2 __attribute__((ext_vector_type(2)));

__device__ __forceinline__ float dot2(h2 a, h2 b, float c) {
#if __has_builtin(__builtin_amdgcn_fdot2)
    return __builtin_amdgcn_fdot2(a, b, c, false);   // v_dot2_f32_f16
#else
    return c + (float)a.x * (float)b.x + (float)a.y * (float)b.y;
#endif
}

__device__ __forceinline__ h2 pack2(float a, float b) {
    h2 v; v.x = (_Float16)a; v.y = (_Float16)b; return v;
}

// -------------------------------------------------------------------------
// Kernel 0: pack fp32 weights into K-paired fp16 half2 in workspace.
// -------------------------------------------------------------------------
__global__ __launch_bounds__(256) void convert_kernel(
    const float* __restrict__ W1, const float* __restrict__ W2,
    const float* __restrict__ Wo,
    h2* __restrict__ W1p, h2* __restrict__ W2p, h2* __restrict__ Wop)
{
    int idx = blockIdx.x * 256 + threadIdx.x;
    if (idx < 131072) {                       // W1: 128 x 1024
        int c2 = idx >> 10, jc = idx & 1023;
        W1p[idx] = pack2(W1[(2 * c2) * HID + jc], W1[(2 * c2 + 1) * HID + jc]);
    } else if (idx < 262144) {                // W2: 512 x 256
        int l = idx - 131072;
        int c2 = l >> 8, jc = l & 255;
        W2p[l] = pack2(W2[(2 * c2) * INNER + jc], W2[(2 * c2 + 1) * INNER + jc]);
    } else if (idx < 294912) {                // Wo: 128 x 256
        int l = idx - 262144;
        int c2 = l >> 8, jc = l & 255;
        Wop[l] = pack2(Wo[(2 * c2) * INNER + jc], Wo[(2 * c2 + 1) * INNER + jc]);
    }
}

// -------------------------------------------------------------------------
// Kernel 1: single-query (l=0) attention, algebraically collapsed.
//
// RoPE rotation-invariance: score[h,m] = sum_j [ (qa_e ka_e + qa_o ka_o) cosD
//   + (qa_o ka_e - qa_e ka_o) sinD ],  D = (t_m - t_0) * invf_j, qa/ka
//   UNROTATED. Rank-2 K (ka = x0*wk0 + x1*wk1) factors this into per-(h,j)
//   constants A0,B0,A1,B1:
//     score[h,m] = x0_m * sum_j(c*A0 + s*B0) + x1_m * sum_j(c*A1 + s*B1)
// Rank-2 V collapses PV: ctx[h,d] = (S0_h*wv0 + S1_h*wv1)/den_h with
//   S0 = sum_m w_m x0_m, S1 = sum_m w_m x1_m.
// 256 threads/block, one block per bn. Half-wave (32 lanes) per head.
// -------------------------------------------------------------------------
__global__ __launch_bounds__(256) void attn_kernel(
    const float* __restrict__ x,      // (BN, PL, 2)
    const float* __restrict__ t,      // (BN, L)
    const int*   __restrict__ mask,   // (BN, L)
    const float* __restrict__ emb,    // (2,)
    const float* __restrict__ Wq,     // (2, 256)
    const float* __restrict__ Wk,     // (2, 256)
    const float* __restrict__ Wv,     // (2, 256)
    float*       __restrict__ last)   // (BN, 256)
{
    const int bn  = blockIdx.x;
    const int tid = threadIdx.x;

    __shared__ float2 cs_s[16][132];   // [j][m] (cosD, sinD); 132 pad: 2-way max
    __shared__ float2 x_s[132];        // x pairs; x_s[0] = emb
    __shared__ float4 ab_s[8][16];     // (A0,B0,A1,B1) per (h,j), scaled
    __shared__ float  sc_s[8][132];    // scores
    __shared__ int    mask_s[132];
    __shared__ float  hstat_s[8][3];   // den, S0, S1 per head

    const float* tb = t + bn * LSEQ;
    const float t0  = tb[0];
    const float e0 = emb[0], e1 = emb[1];

    // ---- Phase A: stage x/mask, build cs table and AB table ----
    if (tid < 130) {
        float2 v;
        if (tid == 0)       v = make_float2(e0, e1);
        else if (tid <= 128) v = ((const float2*)(x + bn * PLEN * 2))[tid - 1];
        else                 v = make_float2(0.f, 0.f);
        x_s[tid] = v;
    }
    if (tid < 129) mask_s[tid] = mask[bn * LSEQ + tid];

    for (int i = tid; i < 129 * 16; i += 256) {
        int m = i >> 4, j = i & 15;
        float invf = exp2f(-(float)j * 0.8304820237218407f); // 10000^(-2j/32)
        float sv, cv;
        __sincosf((tb[m] - t0) * invf, &sv, &cv);
        cs_s[j][m] = make_float2(cv, sv);
    }

    if (tid < 128) {
        int h = tid >> 4, j = tid & 15;
        int ce = h * 32 + 2 * j, co = ce + 1;
        float qe = e0 * Wq[ce] + e1 * Wq[256 + ce];
        float qo = e0 * Wq[co] + e1 * Wq[256 + co];
        float k0e = Wk[ce], k0o = Wk[co];
        float k1e = Wk[256 + ce], k1o = Wk[256 + co];
        const float sc = 0.17677669529663687f;   // 1/sqrt(32)
        ab_s[h][j] = make_float4((qe * k0e + qo * k0o) * sc,
                                 (qo * k0e - qe * k0o) * sc,
                                 (qe * k1e + qo * k1o) * sc,
                                 (qo * k1e - qe * k1o) * sc);
    }
    __syncthreads();

    // ---- Phase B: scores. Half-wave per head; lane handles m = l32+32k ----
    const int lane = tid & 63;
    const int wv   = tid >> 6;
    const int h    = wv * 2 + (lane >> 5);
    const int l32  = lane & 31;

    float4 ab[16];
#pragma unroll
    for (int j = 0; j < 16; ++j) ab[j] = ab_s[h][j];  // 2-addr broadcast

#pragma unroll
    for (int k = 0; k < 5; ++k) {
        int m = l32 + 32 * k;
        if (m < 129) {
            float2 xv = x_s[m];
            float accA = 0.f, accB = 0.f;
#pragma unroll
            for (int j = 0; j < 16; ++j) {
                float2 cs = cs_s[j][m];
                accA = fmaf(cs.x, ab[j].x, accA);
                accA = fmaf(cs.y, ab[j].y, accA);
                accB = fmaf(cs.x, ab[j].z, accB);
                accB = fmaf(cs.y, ab[j].w, accB);
            }
            sc_s[h][m] = accA * xv.x + accB * xv.y;
        }
    }
    __syncthreads();

    // ---- Phase C: per-head softmax + S0/S1 (reduce over 32 lanes) ----
    const int mask0 = mask_s[0];
    float se[5];
    float M = -1e30f;
#pragma unroll
    for (int k = 0; k < 5; ++k) {
        int m = l32 + 32 * k;
        float s;
        if (m < 129) {
            s = sc_s[h][m];
            if (mask0 == 0)          s = 0.f;     // all masked -> uniform
            else if (mask_s[m] == 0) s = -1e9f;   // exp underflows to 0
        } else s = -1e30f;
        se[k] = s;
        M = fmaxf(M, s);
    }
#pragma unroll
    for (int off = 16; off >= 1; off >>= 1) M = fmaxf(M, __shfl_xor(M, off, 64));

    float den = 0.f, S0 = 0.f, S1 = 0.f;
#pragma unroll
    for (int k = 0; k < 5; ++k) {
        int m = l32 + 32 * k;
        if (m < 129) {
            float e = __expf(se[k] - M);
            float2 xv = x_s[m];
            den += e;
            S0 = fmaf(e, xv.x, S0);
            S1 = fmaf(e, xv.y, S1);
        }
    }
#pragma unroll
    for (int off = 16; off >= 1; off >>= 1) {
        den += __shfl_xor(den, off, 64);
        S0  += __shfl_xor(S0,  off, 64);
        S1  += __shfl_xor(S1,  off, 64);
    }
    if (l32 == 0) {
        hstat_s[h][0] = den; hstat_s[h][1] = S0; hstat_s[h][2] = S1;
    }
    __syncthreads();

    // ---- Phase D: ctx via rank-2 V ----
    {
        int hh = tid >> 5;
        float inv = 1.f / hstat_s[hh][0];
        last[bn * 256 + tid] =
            (hstat_s[hh][1] * Wv[tid] + hstat_s[hh][2] * Wv[256 + tid]) * inv;
    }
}

// -------------------------------------------------------------------------
// Kernel 2: LayerNorm -> FF1(256->1024)+ReLU -> FF2(1024->256) -> +residual
//           -> Wo (256->256). 4 rows/block, 1024 threads, fp16 dot2.
// -------------------------------------------------------------------------
__global__ __launch_bounds__(1024) void mlp_kernel(
    const float* __restrict__ last,  // (BN, 256)
    const float* __restrict__ ln_g,  // (256,)
    const float* __restrict__ ln_b,  // (256,)
    const h2*    __restrict__ W1p,   // (128, 1024) K-paired
    const float* __restrict__ b1,    // (1024,)
    const h2*    __restrict__ W2p,   // (512, 256)  K-paired
    const float* __restrict__ b2,    // (256,)
    const h2*    __restrict__ Wop,   // (128, 256)  K-paired
    float*       __restrict__ out)   // (BN, 256)
{
    const int tid = threadIdx.x;      // 0..1023
    const int r0  = blockIdx.x * 4;
    const int rg  = tid >> 8;         // row (LN) / k-chunk (FF2, Wo)
    const int ch  = tid & 255;

    __shared__ float x_s[4][INNER];     //  4 KB raw rows
    __shared__ h2    h2_s[4][128];      //  2 KB post-LN (fp16 pairs)
    __shared__ h2    y2_s[4][512];      //  8 KB post-ReLU hidden
    __shared__ float p_s[4][4][INNER];  // 16 KB partials [kc][row][col]
    __shared__ h2    r2_s[4][128];      //  2 KB residual (fp16 pairs)
    __shared__ float red_s[16][2];

    // ---- load 4 rows ----
    float xv = last[(r0 + rg) * INNER + ch];
    x_s[rg][ch] = xv;

    // ---- LayerNorm (row rg spans waves 4rg..4rg+3) ----
    float s1 = xv, s2 = xv * xv;
#pragma unroll
    for (int off = 32; off >= 1; off >>= 1) {
        s1 += __shfl_xor(s1, off, 64);
        s2 += __shfl_xor(s2, off, 64);
    }
    const int wave = tid >> 6;
    if ((tid & 63) == 0) { red_s[wave][0] = s1; red_s[wave][1] = s2; }
    __syncthreads();

    {
        float t1 = red_s[4 * rg + 0][0] + red_s[4 * rg + 1][0] +
                   red_s[4 * rg + 2][0] + red_s[4 * rg + 3][0];
        float t2 = red_s[4 * rg + 0][1] + red_s[4 * rg + 1][1] +
                   red_s[4 * rg + 2][1] + red_s[4 * rg + 3][1];
        float mu  = t1 * (1.f / 256.f);
        float var = t2 * (1.f / 256.f) - mu * mu;
        float rs  = rsqrtf(var + 1e-5f);
        float hv  = (xv - mu) * rs * ln_g[ch] + ln_b[ch];
        float ho  = __shfl_xor(hv, 1, 64);          // neighbor channel
        if ((ch & 1) == 0) h2_s[rg][ch >> 1] = pack2(hv, ho);
    }
    __syncthreads();

    // ---- FF1: thread owns hidden col tid; 4 row-accumulators ----
    {
        float a0, a1v, a2v, a3;
        a0 = a1v = a2v = a3 = b1[tid];
        const h2* w = W1p + tid;
#pragma unroll 16
        for (int c2 = 0; c2 < 128; ++c2) {
            h2 wv = w[c2 * HID];
            a0  = dot2(h2_s[0][c2], wv, a0);
            a1v = dot2(h2_s[1][c2], wv, a1v);
            a2v = dot2(h2_s[2][c2], wv, a2v);
            a3  = dot2(h2_s[3][c2], wv, a3);
        }
        a0 = fmaxf(a0, 0.f); a1v = fmaxf(a1v, 0.f);
        a2v = fmaxf(a2v, 0.f); a3 = fmaxf(a3, 0.f);
        float o0 = __shfl_xor(a0, 1, 64);
        float o1 = __shfl_xor(a1v, 1, 64);
        float o2 = __shfl_xor(a2v, 1, 64);
        float o3 = __shfl_xor(a3, 1, 64);
        if ((tid & 1) == 0) {
            int p = tid >> 1;
            y2_s[0][p] = pack2(a0, o0);
            y2_s[1][p] = pack2(a1v, o1);
            y2_s[2][p] = pack2(a2v, o2);
            y2_s[3][p] = pack2(a3, o3);
        }
    }
    __syncthreads();

    // ---- FF2: thread (kc=rg, col=ch), K-chunk of 128 pairs; 4 rows ----
    {
        float a0 = 0.f, a1v = 0.f, a2v = 0.f, a3 = 0.f;
        const h2* w = W2p + rg * 128 * INNER + ch;
#pragma unroll 16
        for (int i = 0; i < 128; ++i) {
            h2 wv = w[i * INNER];
            int c2 = rg * 128 + i;
            a0  = dot2(y2_s[0][c2], wv, a0);
            a1v = dot2(y2_s[1][c2], wv, a1v);
            a2v = dot2(y2_s[2][c2], wv, a2v);
            a3  = dot2(y2_s[3][c2], wv, a3);
        }
        p_s[rg][0][ch] = a0;
        p_s[rg][1][ch] = a1v;
        p_s[rg][2][ch] = a2v;
        p_s[rg][3][ch] = a3;
    }
    __syncthreads();

    // ---- combine + bias + residual; repack to fp16 pairs ----
    {
        float rv = x_s[rg][ch] + b2[ch] +
                   p_s[0][rg][ch] + p_s[1][rg][ch] +
                   p_s[2][rg][ch] + p_s[3][rg][ch];
        float ro = __shfl_xor(rv, 1, 64);
        if ((ch & 1) == 0) r2_s[rg][ch >> 1] = pack2(rv, ro);
    }
    __syncthreads();

    // ---- Wo: thread (kc=rg, col=ch), K-chunk of 32 pairs; 4 rows ----
    {
        float a0 = 0.f, a1v = 0.f, a2v = 0.f, a3 = 0.f;
        const h2* w = Wop + rg * 32 * INNER + ch;
#pragma unroll
        for (int i = 0; i < 32; ++i) {
            h2 wv = w[i * INNER];
            int c2 = rg * 32 + i;
            a0  = dot2(r2_s[0][c2], wv, a0);
            a1v = dot2(r2_s[1][c2], wv, a1v);
            a2v = dot2(r2_s[2][c2], wv, a2v);
            a3  = dot2(r2_s[3][c2], wv, a3);
        }
        p_s[rg][0][ch] = a0;
        p_s[rg][1][ch] = a1v;
        p_s[rg][2][ch] = a2v;
        p_s[rg][3][ch] = a3;
    }
    __syncthreads();

    out[(r0 + rg) * INNER + ch] = p_s[0][rg][ch] + p_s[1][rg][ch] +
                                  p_s[2][rg][ch] + p_s[3][rg][ch];
}

// -------------------------------------------------------------------------
extern "C" void kernel_launch(void* const* d_in, const int* in_sizes, int n_in,
                              void* d_out, int out_size, void* d_ws, size_t ws_size,
                              hipStream_t stream) {
    const float* x    = (const float*)d_in[0];
    const float* t    = (const float*)d_in[1];
    const int*   mask = (const int*)  d_in[2];
    const float* emb  = (const float*)d_in[3];
    const float* Wq   = (const float*)d_in[4];
    const float* Wk   = (const float*)d_in[5];
    const float* Wv   = (const float*)d_in[6];
    const float* Wo   = (const float*)d_in[7];
    const float* ln_g = (const float*)d_in[8];
    const float* ln_b = (const float*)d_in[9];
    const float* W1   = (const float*)d_in[10];
    const float* b1   = (const float*)d_in[11];
    const float* W2   = (const float*)d_in[12];
    const float* b2   = (const float*)d_in[13];
    float* out = (float*)d_out;

    const int BN = in_sizes[1] / LSEQ;   // 1024

    char* ws = (char*)d_ws;
    float* last_ws = (float*)ws;                      // 1 MB
    h2* W1p = (h2*)(ws + (1u << 20));                 // 0.5 MB
    h2* W2p = (h2*)(ws + (1u << 20) + (512u << 10));  // 0.5 MB
    h2* Wop = (h2*)(ws + (2u << 20));                 // 0.125 MB

    convert_kernel<<<1152, 256, 0, stream>>>(W1, W2, Wo, W1p, W2p, Wop);
    attn_kernel<<<BN, 256, 0, stream>>>(x, t, mask, emb, Wq, Wk, Wv, last_ws);
    mlp_kernel<<<BN / 4, 1024, 0, stream>>>(last_ws, ln_g, ln_b, W1p, b1,
                                            W2p, b2, Wop, out);
}

// Round 5
// 108.048 us; speedup vs baseline: 2.1221x; 1.0348x over previous
//
#include <hip/hip_runtime.h>
#include <math.h>

// Problem constants (from reference)
#define LSEQ   129      // PL + 1
#define PLEN   128
#define NHEAD  8
#define DHEAD  32
#define INNER  256      // NHEAD * V_DIM
#define HID    1024     // 4 * INNER

typedef _Float16 h2 __attribute__((ext_vector_type(2)));
typedef _Float16 h8 __attribute__((ext_vector_type(8)));   // 16 B = 4 VGPRs

__device__ __forceinline__ float fdot2(h2 a, h2 b, float c) {
#if __has_builtin(__builtin_amdgcn_fdot2)
    return __builtin_amdgcn_fdot2(a, b, c, false);   // v_dot2_f32_f16
#else
    return c + (float)a.x * (float)b.x + (float)a.y * (float)b.y;
#endif
}

// 8-element fp16 dot with fp32 accumulate: 4x v_dot2_f32_f16.
__device__ __forceinline__ float dot8(h8 a, h8 b, float c) {
    h2 a0 = __builtin_shufflevector(a, a, 0, 1);
    h2 a1 = __builtin_shufflevector(a, a, 2, 3);
    h2 a2 = __builtin_shufflevector(a, a, 4, 5);
    h2 a3 = __builtin_shufflevector(a, a, 6, 7);
    h2 b0 = __builtin_shufflevector(b, b, 0, 1);
    h2 b1 = __builtin_shufflevector(b, b, 2, 3);
    h2 b2 = __builtin_shufflevector(b, b, 4, 5);
    h2 b3 = __builtin_shufflevector(b, b, 6, 7);
    c = fdot2(a0, b0, c);
    c = fdot2(a1, b1, c);
    c = fdot2(a2, b2, c);
    c = fdot2(a3, b3, c);
    return c;
}

// -------------------------------------------------------------------------
// Kernel 1: single-query (l=0) attention (algebraically collapsed) PLUS
// weight repack prologue (fp32 -> K-oct fp16, 16 B elements).
//
// Repack layouts (K-major octs, columns contiguous for coalescing):
//   W1o[c8*1024 + j]: halves W1[8c8+i][j], i=0..7   (c8<32)
//   W2o[c8*256  + o]: halves W2[8c8+i][o]           (c8<128)
//   Woo[c8*256  + o]: halves Wo[8c8+i][o]           (c8<32)
// 73728 pack items over 1024x256 threads: blocks 0..287 do one item each.
//
// Attention identity (RoPE rotation-invariance + rank-2 K/V):
//   score[h,m] = x0_m*sum_j(c*A0+s*B0) + x1_m*sum_j(c*A1+s*B1),
//   D=(t_m-t_0)*invf_j;  ctx[h,d] = (S0_h*wv0 + S1_h*wv1)/den_h.
// -------------------------------------------------------------------------
__global__ __launch_bounds__(256) void attn_kernel(
    const float* __restrict__ x,      // (BN, PL, 2)
    const float* __restrict__ t,      // (BN, L)
    const int*   __restrict__ mask,   // (BN, L)
    const float* __restrict__ emb,    // (2,)
    const float* __restrict__ Wq,     // (2, 256)
    const float* __restrict__ Wk,     // (2, 256)
    const float* __restrict__ Wv,     // (2, 256)
    const float* __restrict__ W1,     // (256, 1024)
    const float* __restrict__ W2,     // (1024, 256)
    const float* __restrict__ Wo,     // (256, 256)
    float*       __restrict__ last,   // (BN, 256)
    h8*          __restrict__ W1o,
    h8*          __restrict__ W2o,
    h8*          __restrict__ Woo)
{
    const int bn  = blockIdx.x;
    const int tid = threadIdx.x;

    // ---- Weight repack prologue (independent of LDS phases) ----
    {
        int g = bn * 256 + tid;
        if (g < 73728) {
            h8 v;
            if (g < 32768) {                 // W1: c8<32, j<1024
                int c8 = g >> 10, j = g & 1023;
                const float* src = W1 + (8 * c8) * HID + j;
#pragma unroll
                for (int i = 0; i < 8; ++i) v[i] = (_Float16)src[i * HID];
                W1o[g] = v;
            } else if (g < 65536) {          // W2: c8<128, o<256
                int l = g - 32768;
                int c8 = l >> 8, o = l & 255;
                const float* src = W2 + (8 * c8) * INNER + o;
#pragma unroll
                for (int i = 0; i < 8; ++i) v[i] = (_Float16)src[i * INNER];
                W2o[l] = v;
            } else {                         // Wo: c8<32, o<256
                int l = g - 65536;
                int c8 = l >> 8, o = l & 255;
                const float* src = Wo + (8 * c8) * INNER + o;
#pragma unroll
                for (int i = 0; i < 8; ++i) v[i] = (_Float16)src[i * INNER];
                Woo[l] = v;
            }
        }
    }

    __shared__ float2 cs_s[16][132];   // [j][m]; 132 pad -> 2-way max
    __shared__ float2 x_s[132];        // x pairs; x_s[0] = emb
    __shared__ float4 ab_s[8][16];     // (A0,B0,A1,B1) per (h,j), scaled
    __shared__ float  sc_s[8][132];    // scores
    __shared__ int    mask_s[132];
    __shared__ float  hstat_s[8][3];   // den, S0, S1 per head

    const float* tb = t + bn * LSEQ;
    const float t0  = tb[0];
    const float e0 = emb[0], e1 = emb[1];

    // ---- Phase A: stage x/mask, build cs table and AB table ----
    if (tid < 130) {
        float2 v;
        if (tid == 0)        v = make_float2(e0, e1);
        else if (tid <= 128) v = ((const float2*)(x + bn * PLEN * 2))[tid - 1];
        else                 v = make_float2(0.f, 0.f);
        x_s[tid] = v;
    }
    if (tid < 129) mask_s[tid] = mask[bn * LSEQ + tid];

    for (int i = tid; i < 129 * 16; i += 256) {
        int m = i >> 4, j = i & 15;
        float invf = exp2f(-(float)j * 0.8304820237218407f); // 10000^(-2j/32)
        float sv, cv;
        __sincosf((tb[m] - t0) * invf, &sv, &cv);
        cs_s[j][m] = make_float2(cv, sv);
    }

    if (tid < 128) {
        int h = tid >> 4, j = tid & 15;
        int ce = h * 32 + 2 * j, co = ce + 1;
        float qe = e0 * Wq[ce] + e1 * Wq[256 + ce];
        float qo = e0 * Wq[co] + e1 * Wq[256 + co];
        float k0e = Wk[ce], k0o = Wk[co];
        float k1e = Wk[256 + ce], k1o = Wk[256 + co];
        const float sc = 0.17677669529663687f;   // 1/sqrt(32)
        ab_s[h][j] = make_float4((qe * k0e + qo * k0o) * sc,
                                 (qo * k0e - qe * k0o) * sc,
                                 (qe * k1e + qo * k1o) * sc,
                                 (qo * k1e - qe * k1o) * sc);
    }
    __syncthreads();

    // ---- Phase B: scores. Half-wave per head; lane handles m = l32+32k ----
    const int lane = tid & 63;
    const int wv   = tid >> 6;
    const int h    = wv * 2 + (lane >> 5);
    const int l32  = lane & 31;

    float4 ab[16];
#pragma unroll
    for (int j = 0; j < 16; ++j) ab[j] = ab_s[h][j];  // broadcast reads

#pragma unroll
    for (int k = 0; k < 5; ++k) {
        int m = l32 + 32 * k;
        if (m < 129) {
            float2 xv = x_s[m];
            float accA = 0.f, accB = 0.f;
#pragma unroll
            for (int j = 0; j < 16; ++j) {
                float2 cs = cs_s[j][m];
                accA = fmaf(cs.x, ab[j].x, accA);
                accA = fmaf(cs.y, ab[j].y, accA);
                accB = fmaf(cs.x, ab[j].z, accB);
                accB = fmaf(cs.y, ab[j].w, accB);
            }
            sc_s[h][m] = accA * xv.x + accB * xv.y;
        }
    }
    __syncthreads();

    // ---- Phase C: per-head softmax + S0/S1 (reduce over 32 lanes) ----
    const int mask0 = mask_s[0];
    float se[5];
    float M = -1e30f;
#pragma unroll
    for (int k = 0; k < 5; ++k) {
        int m = l32 + 32 * k;
        float s;
        if (m < 129) {
            s = sc_s[h][m];
            if (mask0 == 0)          s = 0.f;     // all masked -> uniform
            else if (mask_s[m] == 0) s = -1e9f;   // exp underflows to 0
        } else s = -1e30f;
        se[k] = s;
        M = fmaxf(M, s);
    }
#pragma unroll
    for (int off = 16; off >= 1; off >>= 1) M = fmaxf(M, __shfl_xor(M, off, 64));

    float den = 0.f, S0 = 0.f, S1 = 0.f;
#pragma unroll
    for (int k = 0; k < 5; ++k) {
        int m = l32 + 32 * k;
        if (m < 129) {
            float e = __expf(se[k] - M);
            float2 xv = x_s[m];
            den += e;
            S0 = fmaf(e, xv.x, S0);
            S1 = fmaf(e, xv.y, S1);
        }
    }
#pragma unroll
    for (int off = 16; off >= 1; off >>= 1) {
        den += __shfl_xor(den, off, 64);
        S0  += __shfl_xor(S0,  off, 64);
        S1  += __shfl_xor(S1,  off, 64);
    }
    if (l32 == 0) {
        hstat_s[h][0] = den; hstat_s[h][1] = S0; hstat_s[h][2] = S1;
    }
    __syncthreads();

    // ---- Phase D: ctx via rank-2 V ----
    {
        int hh = tid >> 5;
        float inv = 1.f / hstat_s[hh][0];
        last[bn * 256 + tid] =
            (hstat_s[hh][1] * Wv[tid] + hstat_s[hh][2] * Wv[256 + tid]) * inv;
    }
}

// -------------------------------------------------------------------------
// Kernel 2: LayerNorm -> FF1(256->1024)+ReLU -> FF2(1024->256) -> +residual
//           -> Wo (256->256). 4 rows/block, 1024 threads. K-oct fp16
//           weights (dwordx4 loads), activations staged as contiguous fp16
//           rows read via wave-uniform ds_read_b128 (broadcast, no bank
//           conflicts).
// -------------------------------------------------------------------------
__global__ __launch_bounds__(1024) void mlp_kernel(
    const float* __restrict__ last,  // (BN, 256)
    const float* __restrict__ ln_g,  // (256,)
    const float* __restrict__ ln_b,  // (256,)
    const h8*    __restrict__ W1o,   // (32, 1024) K-octs
    const float* __restrict__ b1,    // (1024,)
    const h8*    __restrict__ W2o,   // (128, 256) K-octs
    const float* __restrict__ b2,    // (256,)
    const h8*    __restrict__ Woo,   // (32, 256)  K-octs
    float*       __restrict__ out)   // (BN, 256)
{
    const int tid = threadIdx.x;      // 0..1023
    const int r0  = blockIdx.x * 4;
    const int rg  = tid >> 8;         // row (LN) / k-chunk (FF2, Wo)
    const int ch  = tid & 255;

    __shared__ float x_s[4][INNER];                  //  4 KB raw rows
    __shared__ alignas(16) _Float16 h_h[4][INNER];   //  2 KB post-LN
    __shared__ alignas(16) _Float16 y_h[4][HID];     //  8 KB post-ReLU
    __shared__ alignas(16) _Float16 r_h[4][INNER];   //  2 KB residual
    __shared__ float p_s[4][4][INNER];               // 16 KB partials
    __shared__ float red_s[16][2];

    // ---- load 4 rows ----
    float xv = last[(r0 + rg) * INNER + ch];
    x_s[rg][ch] = xv;

    // ---- LayerNorm (row rg spans waves 4rg..4rg+3) ----
    float s1 = xv, s2 = xv * xv;
#pragma unroll
    for (int off = 32; off >= 1; off >>= 1) {
        s1 += __shfl_xor(s1, off, 64);
        s2 += __shfl_xor(s2, off, 64);
    }
    const int wave = tid >> 6;
    if ((tid & 63) == 0) { red_s[wave][0] = s1; red_s[wave][1] = s2; }
    __syncthreads();

    {
        float t1 = red_s[4 * rg + 0][0] + red_s[4 * rg + 1][0] +
                   red_s[4 * rg + 2][0] + red_s[4 * rg + 3][0];
        float t2 = red_s[4 * rg + 0][1] + red_s[4 * rg + 1][1] +
                   red_s[4 * rg + 2][1] + red_s[4 * rg + 3][1];
        float mu  = t1 * (1.f / 256.f);
        float var = t2 * (1.f / 256.f) - mu * mu;
        float rs  = rsqrtf(var + 1e-5f);
        h_h[rg][ch] = (_Float16)((xv - mu) * rs * ln_g[ch] + ln_b[ch]);
    }
    __syncthreads();

    // ---- FF1: thread owns hidden col tid; 4 row-accumulators ----
    {
        float a0, a1v, a2v, a3;
        a0 = a1v = a2v = a3 = b1[tid];
        const h8* w = W1o + tid;
#pragma unroll 8
        for (int c8 = 0; c8 < 32; ++c8) {
            h8 wv = w[c8 * HID];
            h8 h0 = *(const h8*)&h_h[0][c8 * 8];
            h8 h1 = *(const h8*)&h_h[1][c8 * 8];
            h8 hh2 = *(const h8*)&h_h[2][c8 * 8];
            h8 h3 = *(const h8*)&h_h[3][c8 * 8];
            a0  = dot8(h0, wv, a0);
            a1v = dot8(h1, wv, a1v);
            a2v = dot8(hh2, wv, a2v);
            a3  = dot8(h3, wv, a3);
        }
        y_h[0][tid] = (_Float16)fmaxf(a0, 0.f);
        y_h[1][tid] = (_Float16)fmaxf(a1v, 0.f);
        y_h[2][tid] = (_Float16)fmaxf(a2v, 0.f);
        y_h[3][tid] = (_Float16)fmaxf(a3, 0.f);
    }
    __syncthreads();

    // ---- FF2: thread (kc=rg, col=ch), K-chunk of 32 octs; 4 rows ----
    {
        float a0 = 0.f, a1v = 0.f, a2v = 0.f, a3 = 0.f;
        const h8* w = W2o + rg * 32 * INNER + ch;
#pragma unroll 8
        for (int i = 0; i < 32; ++i) {
            int c8 = rg * 32 + i;
            h8 wv = w[i * INNER];
            h8 y0 = *(const h8*)&y_h[0][c8 * 8];
            h8 y1 = *(const h8*)&y_h[1][c8 * 8];
            h8 y2 = *(const h8*)&y_h[2][c8 * 8];
            h8 y3 = *(const h8*)&y_h[3][c8 * 8];
            a0  = dot8(y0, wv, a0);
            a1v = dot8(y1, wv, a1v);
            a2v = dot8(y2, wv, a2v);
            a3  = dot8(y3, wv, a3);
        }
        p_s[rg][0][ch] = a0;
        p_s[rg][1][ch] = a1v;
        p_s[rg][2][ch] = a2v;
        p_s[rg][3][ch] = a3;
    }
    __syncthreads();

    // ---- combine + bias + residual (fp32), repack to fp16 ----
    {
        float rv = x_s[rg][ch] + b2[ch] +
                   p_s[0][rg][ch] + p_s[1][rg][ch] +
                   p_s[2][rg][ch] + p_s[3][rg][ch];
        r_h[rg][ch] = (_Float16)rv;
    }
    __syncthreads();

    // ---- Wo: thread (kc=rg, col=ch), K-chunk of 8 octs; 4 rows ----
    {
        float a0 = 0.f, a1v = 0.f, a2v = 0.f, a3 = 0.f;
        const h8* w = Woo + rg * 8 * INNER + ch;
#pragma unroll
        for (int i = 0; i < 8; ++i) {
            int c8 = rg * 8 + i;
            h8 wv = w[i * INNER];
            h8 v0 = *(const h8*)&r_h[0][c8 * 8];
            h8 v1 = *(const h8*)&r_h[1][c8 * 8];
            h8 v2 = *(const h8*)&r_h[2][c8 * 8];
            h8 v3 = *(const h8*)&r_h[3][c8 * 8];
            a0  = dot8(v0, wv, a0);
            a1v = dot8(v1, wv, a1v);
            a2v = dot8(v2, wv, a2v);
            a3  = dot8(v3, wv, a3);
        }
        p_s[rg][0][ch] = a0;
        p_s[rg][1][ch] = a1v;
        p_s[rg][2][ch] = a2v;
        p_s[rg][3][ch] = a3;
    }
    __syncthreads();

    out[(r0 + rg) * INNER + ch] = p_s[0][rg][ch] + p_s[1][rg][ch] +
                                  p_s[2][rg][ch] + p_s[3][rg][ch];
}

// -------------------------------------------------------------------------
extern "C" void kernel_launch(void* const* d_in, const int* in_sizes, int n_in,
                              void* d_out, int out_size, void* d_ws, size_t ws_size,
                              hipStream_t stream) {
    const float* x    = (const float*)d_in[0];
    const float* t    = (const float*)d_in[1];
    const int*   mask = (const int*)  d_in[2];
    const float* emb  = (const float*)d_in[3];
    const float* Wq   = (const float*)d_in[4];
    const float* Wk   = (const float*)d_in[5];
    const float* Wv   = (const float*)d_in[6];
    const float* Wo   = (const float*)d_in[7];
    const float* ln_g = (const float*)d_in[8];
    const float* ln_b = (const float*)d_in[9];
    const float* W1   = (const float*)d_in[10];
    const float* b1   = (const float*)d_in[11];
    const float* W2   = (const float*)d_in[12];
    const float* b2   = (const float*)d_in[13];
    float* out = (float*)d_out;

    const int BN = in_sizes[1] / LSEQ;   // 1024

    char* ws = (char*)d_ws;
    float* last_ws = (float*)ws;             // 1 MB
    h8* W1o = (h8*)(ws + (1u << 20));        // 512 KB (32768 x 16 B)
    h8* W2o = (h8*)(ws + (1u << 20) + (512u << 10));   // 512 KB
    h8* Woo = (h8*)(ws + (2u << 20));        // 128 KB

    attn_kernel<<<BN, 256, 0, stream>>>(x, t, mask, emb, Wq, Wk, Wv,
                                        W1, W2, Wo, last_ws, W1o, W2o, Woo);
    mlp_kernel<<<BN / 4, 1024, 0, stream>>>(last_ws, ln_g, ln_b, W1o, b1,
                                            W2o, b2, Woo, out);
}